// Round 1
// baseline (1301.024 us; speedup 1.0000x reference)
//
#include <hip/hip_runtime.h>
#include <hip/hip_bf16.h>
#include <cstdint>

typedef __attribute__((ext_vector_type(4))) float f32x4;
typedef __attribute__((ext_vector_type(8))) short s16x8;

#define LOG2E 1.44269504088896340736f

__device__ __forceinline__ unsigned short f2bf(float f) {
    unsigned int u = __builtin_bit_cast(unsigned int, f);
    u += 0x7FFFu + ((u >> 16) & 1u);
    return (unsigned short)(u >> 16);
}

// ---------------- prep kernels ----------------

__global__ void convert_x_kernel(const float* __restrict__ x,
                                 unsigned short* __restrict__ xb, int n4) {
    int i = blockIdx.x * blockDim.x + threadIdx.x;
    if (i < n4) {
        const float4 v = reinterpret_cast<const float4*>(x)[i];
        ushort4 o;
        o.x = f2bf(v.x); o.y = f2bf(v.y); o.z = f2bf(v.z); o.w = f2bf(v.w);
        reinterpret_cast<ushort4*>(xb)[i] = o;
    }
}

// WT layout: [3][512 n][512 k], WT[m][n][k] = W_m[k][n]  (bf16)
__global__ void transpose_w_kernel(const float* __restrict__ Wq,
                                   const float* __restrict__ Wk,
                                   const float* __restrict__ Wv,
                                   unsigned short* __restrict__ WT) {
    int i = blockIdx.x * blockDim.x + threadIdx.x;   // 0..786431
    int m = i >> 18;
    int r = i & 262143;
    int n = r & 511;
    int k = r >> 9;
    const float* W = (m == 0) ? Wq : (m == 1) ? Wk : Wv;
    WT[(m << 18) + n * 512 + k] = f2bf(W[k * 512 + n]);
}

// ---------------- projection GEMM ----------------
// C[16384][512] = xb @ W + b, three outputs selected by blockIdx.z.
// z=0 -> Qb row-major, z=1 -> Kb row-major, z=2 -> VT[b][d][n] transposed.
__global__ __launch_bounds__(256, 2) void proj_gemm_kernel(
    const unsigned short* __restrict__ xb,   // [16384][512] bf16
    const unsigned short* __restrict__ WT,   // [3][512][512] bf16 (n-major)
    const float* __restrict__ bq, const float* __restrict__ bk, const float* __restrict__ bv,
    unsigned short* __restrict__ Qb, unsigned short* __restrict__ Kb,
    unsigned short* __restrict__ VT)
{
    const int z = blockIdx.z;
    const unsigned short* Wt = WT + (z << 18);
    const float* bias = (z == 0) ? bq : (z == 1) ? bk : bv;

    const int gm = blockIdx.x * 128;
    const int gn = blockIdx.y * 128;
    const int wave = threadIdx.x >> 6, lane = threadIdx.x & 63;
    const int wr = wave >> 1, wc = wave & 1;
    const int lr = lane & 15, lg = lane >> 4;
    const int row0 = gm + wr * 64;
    const int col0 = gn + wc * 64;

    f32x4 acc[4][4];
    #pragma unroll
    for (int mi = 0; mi < 4; mi++)
        #pragma unroll
        for (int ni = 0; ni < 4; ni++)
            acc[mi][ni] = (f32x4){0.f, 0.f, 0.f, 0.f};

    for (int k0 = 0; k0 < 512; k0 += 32) {
        s16x8 a[4], b[4];
        #pragma unroll
        for (int mi = 0; mi < 4; mi++)
            a[mi] = *reinterpret_cast<const s16x8*>(xb + (size_t)(row0 + mi * 16 + lr) * 512 + k0 + lg * 8);
        #pragma unroll
        for (int ni = 0; ni < 4; ni++)
            b[ni] = *reinterpret_cast<const s16x8*>(Wt + (size_t)(col0 + ni * 16 + lr) * 512 + k0 + lg * 8);
        #pragma unroll
        for (int mi = 0; mi < 4; mi++)
            #pragma unroll
            for (int ni = 0; ni < 4; ni++)
                acc[mi][ni] = __builtin_amdgcn_mfma_f32_16x16x32_bf16(a[mi], b[ni], acc[mi][ni], 0, 0, 0);
    }

    #pragma unroll
    for (int ni = 0; ni < 4; ni++) {
        const int col = col0 + ni * 16 + lr;
        const float bs = bias[col];
        #pragma unroll
        for (int mi = 0; mi < 4; mi++) {
            const int rowb = row0 + mi * 16 + lg * 4;
            if (z == 2) {
                // VT[b][col][n], rows rowb..rowb+3 are contiguous n
                unsigned short h[4];
                #pragma unroll
                for (int j = 0; j < 4; j++) h[j] = f2bf(acc[mi][ni][j] + bs);
                const int bb = rowb >> 11;
                const int nn = rowb & 2047;
                ushort4 o; o.x = h[0]; o.y = h[1]; o.z = h[2]; o.w = h[3];
                *reinterpret_cast<ushort4*>(VT + (size_t)bb * (512 * 2048) + (size_t)col * 2048 + nn) = o;
            } else {
                unsigned short* dst = (z == 0) ? Qb : Kb;
                #pragma unroll
                for (int j = 0; j < 4; j++)
                    dst[(size_t)(rowb + j) * 512 + col] = f2bf(acc[mi][ni][j] + bs);
            }
        }
    }
}

// ---------------- fused masked attention ----------------
// grid (32 q-tiles, 8 batches), 4 waves x 16 q-rows, kv tiles of 64.
__global__ __launch_bounds__(256, 2) void attn_kernel(
    const unsigned short* __restrict__ Qb,   // [B*2048][512] bf16
    const unsigned short* __restrict__ Kb,   // [B*2048][512] bf16
    const unsigned short* __restrict__ VTb,  // [B][512][2048] bf16
    const float* __restrict__ adj,           // [B][2048][2048] f32
    const float* __restrict__ scale_p, const float* __restrict__ width_p,
    float* __restrict__ out)                 // [B][2048][512] f32
{
    const int b    = blockIdx.y;
    const int qt   = blockIdx.x;
    const int wave = threadIdx.x >> 6;
    const int lane = threadIdx.x & 63;
    const int lr   = lane & 15;
    const int lg   = lane >> 4;

    const float scl = *scale_p;
    const float nw  = -LOG2E / (*width_p);            // mask exponent coeff (log2 domain)
    const float cf  = 0.044194173824159216f * LOG2E;  // inv_sqrt(512) * log2(e)

    const int q0 = qt * 64 + wave * 16;               // q base within batch
    const unsigned short* Qrow  = Qb  + ((size_t)b * 2048 + q0) * 512;
    const unsigned short* Kbase = Kb  + (size_t)b * 2048 * 512;
    const unsigned short* Vbase = VTb + (size_t)b * 512 * 2048;
    const float* adj_b = adj + (size_t)b * 2048 * 2048 + (size_t)(q0 + lg * 4) * 2048 + lr;

    __shared__ __align__(16) unsigned short p_lds[4][16][72];  // +8 pad: bank-safe

    // Q fragments in registers: A-operand rows = lr, k = ks*32 + lg*8 + [0..7]
    s16x8 qf[16];
    #pragma unroll
    for (int ks = 0; ks < 16; ks++)
        qf[ks] = *reinterpret_cast<const s16x8*>(Qrow + (size_t)lr * 512 + ks * 32 + lg * 8);

    f32x4 oacc[32];
    #pragma unroll
    for (int i = 0; i < 32; i++) oacc[i] = (f32x4){0.f, 0.f, 0.f, 0.f};
    float m_[4] = {-1e30f, -1e30f, -1e30f, -1e30f};
    float l_[4] = {0.f, 0.f, 0.f, 0.f};

    for (int kt = 0; kt < 32; kt++) {
        const int kv0 = kt * 64;

        // ---- S = Q K^T ----
        f32x4 sacc[4];
        #pragma unroll
        for (int nt = 0; nt < 4; nt++) sacc[nt] = (f32x4){0.f, 0.f, 0.f, 0.f};
        for (int ks = 0; ks < 16; ks++) {
            const s16x8 a = qf[ks];
            #pragma unroll
            for (int nt = 0; nt < 4; nt++) {
                const s16x8 bf = *reinterpret_cast<const s16x8*>(
                    Kbase + (size_t)(kv0 + nt * 16 + lr) * 512 + ks * 32 + lg * 8);
                sacc[nt] = __builtin_amdgcn_mfma_f32_16x16x32_bf16(a, bf, sacc[nt], 0, 0, 0);
            }
        }

        // ---- mask + log2-domain logits (in place) ----
        #pragma unroll
        for (int nt = 0; nt < 4; nt++)
            #pragma unroll
            for (int j = 0; j < 4; j++) {
                const float av = adj_b[(size_t)j * 2048 + kv0 + nt * 16];
                const float d  = av - scl;
                const float msk = exp2f(d * d * nw);
                sacc[nt][j] = sacc[nt][j] * cf * msk;
            }

        // ---- online softmax ----
        float corr[4];
        #pragma unroll
        for (int j = 0; j < 4; j++) {
            float v = fmaxf(fmaxf(sacc[0][j], sacc[1][j]), fmaxf(sacc[2][j], sacc[3][j]));
            #pragma unroll
            for (int s = 1; s < 16; s <<= 1) v = fmaxf(v, __shfl_xor(v, s, 64));
            const float mn = fmaxf(m_[j], v);
            corr[j] = exp2f(m_[j] - mn);
            m_[j] = mn;
        }
        const bool need = __any(corr[0] < 1.f || corr[1] < 1.f || corr[2] < 1.f || corr[3] < 1.f);
        if (need) {
            #pragma unroll
            for (int f = 0; f < 32; f++)
                #pragma unroll
                for (int j = 0; j < 4; j++) oacc[f][j] *= corr[j];
        }

        #pragma unroll
        for (int j = 0; j < 4; j++) {
            float rs = 0.f;
            #pragma unroll
            for (int nt = 0; nt < 4; nt++) {
                const float p = exp2f(sacc[nt][j] - m_[j]);
                p_lds[wave][lg * 4 + j][nt * 16 + lr] = f2bf(p);
                rs += p;
            }
            #pragma unroll
            for (int s = 1; s < 16; s <<= 1) rs += __shfl_xor(rs, s, 64);
            l_[j] = l_[j] * corr[j] + rs;
        }

        // ---- O += P V  (per-wave LDS buffer; in-wave lgkmcnt ordering) ----
        #pragma unroll
        for (int ks = 0; ks < 2; ks++) {
            const s16x8 pa = *reinterpret_cast<const s16x8*>(&p_lds[wave][lr][ks * 32 + lg * 8]);
            #pragma unroll
            for (int df = 0; df < 32; df++) {
                const s16x8 vb = *reinterpret_cast<const s16x8*>(
                    Vbase + (size_t)(df * 16 + lr) * 2048 + kv0 + ks * 32 + lg * 8);
                oacc[df] = __builtin_amdgcn_mfma_f32_16x16x32_bf16(pa, vb, oacc[df], 0, 0, 0);
            }
        }
    }

    // ---- epilogue ----
    float invl[4];
    #pragma unroll
    for (int j = 0; j < 4; j++) invl[j] = 1.f / l_[j];
    float* outp = out + ((size_t)b * 2048 + q0 + lg * 4) * 512 + lr;
    #pragma unroll
    for (int df = 0; df < 32; df++)
        #pragma unroll
        for (int j = 0; j < 4; j++)
            outp[(size_t)j * 512 + df * 16] = oacc[df][j] * invl[j];
}

// ---------------- launch ----------------

extern "C" void kernel_launch(void* const* d_in, const int* in_sizes, int n_in,
                              void* d_out, int out_size, void* d_ws, size_t ws_size,
                              hipStream_t stream) {
    const float* x     = (const float*)d_in[0];
    const float* adj   = (const float*)d_in[1];
    const float* Wq    = (const float*)d_in[2];
    const float* bq    = (const float*)d_in[3];
    const float* Wk    = (const float*)d_in[4];
    const float* bk    = (const float*)d_in[5];
    const float* Wv    = (const float*)d_in[6];
    const float* bv    = (const float*)d_in[7];
    const float* scale = (const float*)d_in[8];
    const float* width = (const float*)d_in[9];

    char* ws = (char*)d_ws;
    unsigned short* xb = (unsigned short*)(ws);                // 16,777,216 B
    unsigned short* WT = (unsigned short*)(ws + 16777216);     //  1,572,864 B
    unsigned short* Qb = (unsigned short*)(ws + 18350080);     // 16,777,216 B
    unsigned short* Kb = (unsigned short*)(ws + 35127296);     // 16,777,216 B
    unsigned short* VT = (unsigned short*)(ws + 51904512);     // 16,777,216 B
    float* out = (float*)d_out;

    hipLaunchKernelGGL(convert_x_kernel, dim3(8192), dim3(256), 0, stream, x, xb, 8388608 / 4);
    hipLaunchKernelGGL(transpose_w_kernel, dim3(3072), dim3(256), 0, stream, Wq, Wk, Wv, WT);
    hipLaunchKernelGGL(proj_gemm_kernel, dim3(128, 4, 3), dim3(256), 0, stream,
                       xb, WT, bq, bk, bv, Qb, Kb, VT);
    hipLaunchKernelGGL(attn_kernel, dim3(32, 8), dim3(256), 0, stream,
                       Qb, Kb, VT, adj, scale, width, out);
}

// Round 2
// 574.568 us; speedup vs baseline: 2.2644x; 2.2644x over previous
//
#include <hip/hip_runtime.h>
#include <hip/hip_bf16.h>
#include <cstdint>

typedef __attribute__((ext_vector_type(4))) float f32x4;
typedef __attribute__((ext_vector_type(8))) short s16x8;

#define LOG2E 1.44269504088896340736f

__device__ __forceinline__ unsigned short f2bf(float f) {
    unsigned int u = __builtin_bit_cast(unsigned int, f);
    u += 0x7FFFu + ((u >> 16) & 1u);
    return (unsigned short)(u >> 16);
}
__device__ __forceinline__ float bf2f(unsigned short u) {
    return __builtin_bit_cast(float, (unsigned int)u << 16);
}
__device__ __forceinline__ void gload_lds16(const void* g, void* l) {
    __builtin_amdgcn_global_load_lds(
        (const __attribute__((address_space(1))) unsigned int*)g,
        (__attribute__((address_space(3))) unsigned int*)l, 16, 0, 0);
}

// ---------------- prep kernels ----------------

__global__ void convert_x_kernel(const float* __restrict__ x,
                                 unsigned short* __restrict__ xb, int n4) {
    int i = blockIdx.x * blockDim.x + threadIdx.x;
    if (i < n4) {
        const float4 v = reinterpret_cast<const float4*>(x)[i];
        ushort4 o;
        o.x = f2bf(v.x); o.y = f2bf(v.y); o.z = f2bf(v.z); o.w = f2bf(v.w);
        reinterpret_cast<ushort4*>(xb)[i] = o;
    }
}

// WT layout: [3][512 n][512 k], WT[m][n][k] = W_m[k][n]  (bf16)
__global__ void transpose_w_kernel(const float* __restrict__ Wq,
                                   const float* __restrict__ Wk,
                                   const float* __restrict__ Wv,
                                   unsigned short* __restrict__ WT) {
    int i = blockIdx.x * blockDim.x + threadIdx.x;   // 0..786431
    int m = i >> 18;
    int r = i & 262143;
    int n = r & 511;
    int k = r >> 9;
    const float* W = (m == 0) ? Wq : (m == 1) ? Wk : Wv;
    WT[(m << 18) + n * 512 + k] = f2bf(W[k * 512 + n]);
}

// ---------------- projection GEMM ----------------
__global__ __launch_bounds__(256, 2) void proj_gemm_kernel(
    const unsigned short* __restrict__ xb,
    const unsigned short* __restrict__ WT,
    const float* __restrict__ bq, const float* __restrict__ bk, const float* __restrict__ bv,
    unsigned short* __restrict__ Qb, unsigned short* __restrict__ Kb,
    unsigned short* __restrict__ VT)
{
    const int z = blockIdx.z;
    const unsigned short* Wt = WT + (z << 18);
    const float* bias = (z == 0) ? bq : (z == 1) ? bk : bv;

    const int gm = blockIdx.x * 128;
    const int gn = blockIdx.y * 128;
    const int wave = threadIdx.x >> 6, lane = threadIdx.x & 63;
    const int wr = wave >> 1, wc = wave & 1;
    const int lr = lane & 15, lg = lane >> 4;
    const int row0 = gm + wr * 64;
    const int col0 = gn + wc * 64;

    f32x4 acc[4][4];
    #pragma unroll
    for (int mi = 0; mi < 4; mi++)
        #pragma unroll
        for (int ni = 0; ni < 4; ni++)
            acc[mi][ni] = (f32x4){0.f, 0.f, 0.f, 0.f};

    for (int k0 = 0; k0 < 512; k0 += 32) {
        s16x8 a[4], b[4];
        #pragma unroll
        for (int mi = 0; mi < 4; mi++)
            a[mi] = *reinterpret_cast<const s16x8*>(xb + (size_t)(row0 + mi * 16 + lr) * 512 + k0 + lg * 8);
        #pragma unroll
        for (int ni = 0; ni < 4; ni++)
            b[ni] = *reinterpret_cast<const s16x8*>(Wt + (size_t)(col0 + ni * 16 + lr) * 512 + k0 + lg * 8);
        #pragma unroll
        for (int mi = 0; mi < 4; mi++)
            #pragma unroll
            for (int ni = 0; ni < 4; ni++)
                acc[mi][ni] = __builtin_amdgcn_mfma_f32_16x16x32_bf16(a[mi], b[ni], acc[mi][ni], 0, 0, 0);
    }

    #pragma unroll
    for (int ni = 0; ni < 4; ni++) {
        const int col = col0 + ni * 16 + lr;
        const float bs = bias[col];
        #pragma unroll
        for (int mi = 0; mi < 4; mi++) {
            const int rowb = row0 + mi * 16 + lg * 4;
            if (z == 2) {
                unsigned short h[4];
                #pragma unroll
                for (int j = 0; j < 4; j++) h[j] = f2bf(acc[mi][ni][j] + bs);
                const int bb = rowb >> 11;
                const int nn = rowb & 2047;
                ushort4 o; o.x = h[0]; o.y = h[1]; o.z = h[2]; o.w = h[3];
                *reinterpret_cast<ushort4*>(VT + (size_t)bb * (512 * 2048) + (size_t)col * 2048 + nn) = o;
            } else {
                unsigned short* dst = (z == 0) ? Qb : Kb;
                #pragma unroll
                for (int j = 0; j < 4; j++)
                    dst[(size_t)(rowb + j) * 512 + col] = f2bf(acc[mi][ni][j] + bs);
            }
        }
    }
}

// ---------------- fused masked attention (kv-split flash) ----------------
// grid (8 batch, 32 qtile, 2 kvhalf); 4 waves x 16 q-rows; kv tiles of 64,
// K/V LDS-staged in 16KB d-chunks, double-buffered, XOR-swizzled.
__global__ __launch_bounds__(256, 2) void attn_kernel(
    const unsigned short* __restrict__ Qb,   // [B*2048][512] bf16
    const unsigned short* __restrict__ Kb,   // [B*2048][512] bf16
    const unsigned short* __restrict__ VTb,  // [B][512][2048] bf16
    const float* __restrict__ adj,           // [B][2048][2048] f32
    const float* __restrict__ scale_p, const float* __restrict__ width_p,
    unsigned short* __restrict__ Op,         // [2][16384][512] bf16 partials
    float* __restrict__ Mp, float* __restrict__ Lp)  // [2][16384]
{
    const int b    = blockIdx.x;
    const int qt   = blockIdx.y;
    const int kvh  = blockIdx.z;
    const int wave = threadIdx.x >> 6;
    const int lane = threadIdx.x & 63;
    const int lr   = lane & 15;
    const int lg   = lane >> 4;

    const float scl = *scale_p;
    const float nw  = -LOG2E / (*width_p);
    const float cf  = 0.044194173824159216f * LOG2E;  // inv_sqrt(512)*log2(e)

    const int q0 = qt * 64 + wave * 16;
    const unsigned short* Qrow = Qb + ((size_t)b * 2048 + q0) * 512;
    const char* Kg = (const char*)Kb  + ((size_t)b * 2048 + (size_t)kvh * 1024) * 1024;
    const char* Vg = (const char*)VTb + ((size_t)b * 512 * 2048 + (size_t)kvh * 1024) * 2;
    const float* adj_b = adj + (size_t)b * 2048 * 2048
                       + (size_t)(q0 + lg * 4) * 2048 + (size_t)kvh * 1024 + lr;

    __shared__ __align__(16) char chunk[2][16384];
    __shared__ __align__(16) unsigned short p_lds[4][16][72];

    const int slot_base = wave * 4;
    // K chunk buffer layout: [64 kv][128 d] bf16, byte_off ^ ((row&7)<<4)
    auto stage_k = [&](int kv0, int dc, int bufi) {
        #pragma unroll
        for (int i = 0; i < 4; i++) {
            const int slot = slot_base + i;
            const int row  = slot * 4 + (lane >> 4);
            const int colb = (lane & 15) * 16;
            gload_lds16(Kg + (size_t)(kv0 + row) * 1024 + dc * 256 + (colb ^ ((row & 7) << 4)),
                        &chunk[bufi][slot * 1024]);
        }
    };
    // V chunk buffer layout: [128 d][64 kv] bf16, byte_off ^ ((row&7)<<4)
    auto stage_v = [&](int kv0, int dc, int bufi) {
        #pragma unroll
        for (int i = 0; i < 4; i++) {
            const int slot = slot_base + i;
            const int row  = slot * 8 + (lane >> 3);
            const int colb = (lane & 7) * 16;
            gload_lds16(Vg + (size_t)(dc * 128 + row) * 4096 + (size_t)kv0 * 2
                           + (colb ^ ((row & 7) << 4)),
                        &chunk[bufi][slot * 1024]);
        }
    };

    s16x8 qf[16];
    #pragma unroll
    for (int ks = 0; ks < 16; ks++)
        qf[ks] = *reinterpret_cast<const s16x8*>(Qrow + (size_t)lr * 512 + ks * 32 + lg * 8);

    f32x4 oacc[32];
    #pragma unroll
    for (int i = 0; i < 32; i++) oacc[i] = (f32x4){0.f, 0.f, 0.f, 0.f};
    float m_[4] = {-1e30f, -1e30f, -1e30f, -1e30f};
    float l_[4] = {0.f, 0.f, 0.f, 0.f};

    stage_k(0, 0, 0);
    __syncthreads();

    for (int t = 0; t < 16; t++) {
        const int kv0 = t * 64;
        float av[4][4];
        f32x4 sacc[4];
        #pragma unroll
        for (int nt = 0; nt < 4; nt++) sacc[nt] = (f32x4){0.f, 0.f, 0.f, 0.f};

        #pragma unroll
        for (int sub = 0; sub < 8; sub++) {
            // issue next-phase staging (async, lands by this phase's barrier)
            if (sub < 3)      stage_k(kv0, sub + 1, (sub + 1) & 1);
            else if (sub < 7) stage_v(kv0, sub - 3, (sub + 1) & 1);
            else if (t < 15)  stage_k(kv0 + 64, 0, 0);

            if (sub == 2) {   // hoist adj loads one phase ahead of use
                #pragma unroll
                for (int nt = 0; nt < 4; nt++)
                    #pragma unroll
                    for (int j = 0; j < 4; j++)
                        av[nt][j] = adj_b[(size_t)j * 2048 + kv0 + nt * 16];
            }

            if (sub < 4) {
                const int dc = sub;
                const char* kb_ = &chunk[sub & 1][0];
                #pragma unroll
                for (int ks = 0; ks < 4; ks++) {
                    const s16x8 a = qf[dc * 4 + ks];
                    #pragma unroll
                    for (int nt = 0; nt < 4; nt++) {
                        const int row = nt * 16 + lr;
                        const int cb  = ks * 64 + lg * 16;
                        const s16x8 kf = *reinterpret_cast<const s16x8*>(
                            kb_ + row * 256 + (cb ^ ((row & 7) << 4)));
                        sacc[nt] = __builtin_amdgcn_mfma_f32_16x16x32_bf16(a, kf, sacc[nt], 0, 0, 0);
                    }
                }
            } else {
                const int dc = sub - 4;
                const char* vb_ = &chunk[sub & 1][0];
                #pragma unroll
                for (int ks2 = 0; ks2 < 2; ks2++) {
                    const s16x8 pa = *reinterpret_cast<const s16x8*>(&p_lds[wave][lr][ks2 * 32 + lg * 8]);
                    #pragma unroll
                    for (int df2 = 0; df2 < 8; df2++) {
                        const int row = df2 * 16 + lr;
                        const int cb  = ks2 * 64 + lg * 16;
                        const s16x8 vf = *reinterpret_cast<const s16x8*>(
                            vb_ + row * 128 + (cb ^ ((row & 7) << 4)));
                        oacc[dc * 8 + df2] = __builtin_amdgcn_mfma_f32_16x16x32_bf16(pa, vf, oacc[dc * 8 + df2], 0, 0, 0);
                    }
                }
            }

            if (sub == 3) {
                // mask + online softmax + stage P through per-wave LDS
                #pragma unroll
                for (int nt = 0; nt < 4; nt++)
                    #pragma unroll
                    for (int j = 0; j < 4; j++) {
                        const float d = av[nt][j] - scl;
                        sacc[nt][j] = sacc[nt][j] * cf * exp2f(d * d * nw);
                    }
                float corr[4];
                #pragma unroll
                for (int j = 0; j < 4; j++) {
                    float v = fmaxf(fmaxf(sacc[0][j], sacc[1][j]), fmaxf(sacc[2][j], sacc[3][j]));
                    #pragma unroll
                    for (int s = 1; s < 16; s <<= 1) v = fmaxf(v, __shfl_xor(v, s, 64));
                    const float mn = fmaxf(m_[j], v);
                    corr[j] = exp2f(m_[j] - mn);
                    m_[j] = mn;
                }
                const bool need = __any(corr[0] < 1.f || corr[1] < 1.f || corr[2] < 1.f || corr[3] < 1.f);
                if (need) {
                    #pragma unroll
                    for (int f = 0; f < 32; f++)
                        #pragma unroll
                        for (int j = 0; j < 4; j++) oacc[f][j] *= corr[j];
                }
                #pragma unroll
                for (int j = 0; j < 4; j++) {
                    float rs = 0.f;
                    #pragma unroll
                    for (int nt = 0; nt < 4; nt++) {
                        const float p = exp2f(sacc[nt][j] - m_[j]);
                        p_lds[wave][lg * 4 + j][nt * 16 + lr] = f2bf(p);
                        rs += p;
                    }
                    #pragma unroll
                    for (int s = 1; s < 16; s <<= 1) rs += __shfl_xor(rs, s, 64);
                    l_[j] = l_[j] * corr[j] + rs;
                }
            }
            __syncthreads();
        }
    }

    // ---- epilogue: unnormalized partial O (bf16) + m/l ----
    const size_t prow = (size_t)kvh * 16384 + (size_t)b * 2048 + q0 + lg * 4;
    unsigned short* op = Op + prow * 512 + lr;
    #pragma unroll
    for (int df = 0; df < 32; df++)
        #pragma unroll
        for (int j = 0; j < 4; j++)
            op[(size_t)j * 512 + df * 16] = f2bf(oacc[df][j]);
    if (lr == 0) {
        #pragma unroll
        for (int j = 0; j < 4; j++) {
            Mp[prow + j] = m_[j];
            Lp[prow + j] = l_[j];
        }
    }
}

// ---------------- combine (flash-decode merge of 2 kv-halves) ----------------
__global__ void combine_kernel(const unsigned short* __restrict__ Op,
                               const float* __restrict__ Mp, const float* __restrict__ Lp,
                               float* __restrict__ out) {
    const int idx = blockIdx.x * 256 + threadIdx.x;   // 1,048,576 threads
    const int r   = idx >> 6;
    const int c8  = (idx & 63) * 8;
    const float m0 = Mp[r], m1 = Mp[16384 + r];
    const float l0 = Lp[r], l1 = Lp[16384 + r];
    const float M  = fmaxf(m0, m1);
    const float e0 = exp2f(m0 - M), e1 = exp2f(m1 - M);
    const float invL = 1.f / (e0 * l0 + e1 * l1);
    const s16x8 a = *reinterpret_cast<const s16x8*>(Op + (size_t)r * 512 + c8);
    const s16x8 bq = *reinterpret_cast<const s16x8*>(Op + (size_t)16384 * 512 + (size_t)r * 512 + c8);
    float o[8];
    #pragma unroll
    for (int i = 0; i < 8; i++)
        o[i] = (bf2f((unsigned short)a[i]) * e0 + bf2f((unsigned short)bq[i]) * e1) * invL;
    f32x4* dst = reinterpret_cast<f32x4*>(out + (size_t)r * 512 + c8);
    dst[0] = (f32x4){o[0], o[1], o[2], o[3]};
    dst[1] = (f32x4){o[4], o[5], o[6], o[7]};
}

// ---------------- launch ----------------

extern "C" void kernel_launch(void* const* d_in, const int* in_sizes, int n_in,
                              void* d_out, int out_size, void* d_ws, size_t ws_size,
                              hipStream_t stream) {
    const float* x     = (const float*)d_in[0];
    const float* adj   = (const float*)d_in[1];
    const float* Wq    = (const float*)d_in[2];
    const float* bq    = (const float*)d_in[3];
    const float* Wk    = (const float*)d_in[4];
    const float* bk    = (const float*)d_in[5];
    const float* Wv    = (const float*)d_in[6];
    const float* bv    = (const float*)d_in[7];
    const float* scale = (const float*)d_in[8];
    const float* width = (const float*)d_in[9];

    char* ws = (char*)d_ws;
    unsigned short* xb = (unsigned short*)(ws);                 // 16,777,216 B
    unsigned short* WT = (unsigned short*)(ws + 16777216);      //  1,572,864 B
    unsigned short* Qb = (unsigned short*)(ws + 18350080);      // 16,777,216 B
    unsigned short* Kb = (unsigned short*)(ws + 35127296);      // 16,777,216 B
    unsigned short* VT = (unsigned short*)(ws + 51904512);      // 16,777,216 B
    unsigned short* Op = (unsigned short*)(ws + 68681728);      // 33,554,432 B
    float*          Mp = (float*)(ws + 102236160);              //    131,072 B
    float*          Lp = (float*)(ws + 102367232);              //    131,072 B
    float* out = (float*)d_out;

    hipLaunchKernelGGL(convert_x_kernel, dim3(8192), dim3(256), 0, stream, x, xb, 8388608 / 4);
    hipLaunchKernelGGL(transpose_w_kernel, dim3(3072), dim3(256), 0, stream, Wq, Wk, Wv, WT);
    hipLaunchKernelGGL(proj_gemm_kernel, dim3(128, 4, 3), dim3(256), 0, stream,
                       xb, WT, bq, bk, bv, Qb, Kb, VT);
    hipLaunchKernelGGL(attn_kernel, dim3(8, 32, 2), dim3(256), 0, stream,
                       Qb, Kb, VT, adj, scale, width, Op, Mp, Lp);
    hipLaunchKernelGGL(combine_kernel, dim3(4096), dim3(256), 0, stream, Op, Mp, Lp, out);
}